// Round 5
// baseline (313.390 us; speedup 1.0000x reference)
//
#include <hip/hip_runtime.h>

// LDPC neural BP decoder, MI355X. Round 5.
// Rounds 1-4: VGPR budget is pinned at 64 by the toolchain no matter what
// launch_bounds / waves_per_eu say, so 45 persistent f32/thread always
// spilled (~190 MB excess WRITE). Fix: shrink persistent state to vm+vmp
// (18 regs); wl/wr0/wr1 are reloaded per iteration from L2-resident globals
// (block working set ~1.5 MB/XCD -> L2 hits). Peak live ~43 regs < 64 ->
// zero spill by construction. Default occupancy (2 blocks/CU) for barrier
// overlap. One block per batch row; t-row in LDS; t computed per node per
// iteration (10x fewer tanh than per-edge).

#define NN    8448
#define MAXNB 10
#define TPB   1024
#define MAXK  9       // ceil(8448/1024); k=8 active only for tid<256
#define ITERS 5

__global__ __launch_bounds__(TPB)
void ldpc_decode_kernel(const float* __restrict__ input_llr,
                        const float* __restrict__ w_ch,
                        const float* __restrict__ w_res,   // [2][NN]
                        const int*   __restrict__ cidx,    // [NN][10]
                        float* __restrict__ out)
{
    __shared__ float t_lds[NN];
    const int row = blockIdx.x;
    const int tid = threadIdx.x;
    const float* __restrict__ in_row = input_llr + (size_t)row * NN;

    // persistent state: ONLY vm and vmp (18 VGPRs)
    float vm[MAXK], vmp[MAXK];

    // prologue: vm0 = weighted_llr = input * w_ch; prev = 0
    #pragma unroll
    for (int k = 0; k < MAXK; ++k) {
        int n = tid + k * TPB;
        vmp[k] = 0.0f;
        vm[k]  = 0.0f;
        if (k < MAXK - 1 || n < NN) {
            vm[k] = in_row[n] * w_ch[n];      // coalesced
        }
    }

    for (int it = 0; it < ITERS; ++it) {
        // phase 1: t[n] = tanh(clip(0.5*vm, +-9.9)) = 1 - 2/(exp(clip(vm,+-19.8))+1)
        #pragma unroll
        for (int k = 0; k < MAXK; ++k) {
            int n = tid + k * TPB;
            if (k < MAXK - 1 || n < NN) {
                float y = fminf(fmaxf(vm[k], -19.8f), 19.8f);
                float e = __expf(y);
                t_lds[n] = 1.0f - __fdividef(2.0f, e + 1.0f);
            }
        }
        __syncthreads();

        // phase 2: gather 10 t's, product, 2*atanh, residual update.
        // wl/wr0/wr1 reloaded each iteration (coalesced L2 hits) instead of
        // held in registers -- keeps live set under the 64-VGPR budget.
        #pragma unroll
        for (int k = 0; k < MAXK; ++k) {
            int n = tid + k * TPB;
            if (k < MAXK - 1 || n < NN) {
                // 40*n is 8B-aligned -> five int2 loads (L2-resident, 338 KB table)
                const int2* ip = (const int2*)(cidx + n * MAXNB);
                int2 i0 = ip[0], i1 = ip[1], i2 = ip[2], i3 = ip[3], i4 = ip[4];
                float p0 = t_lds[i0.x] * t_lds[i0.y];
                float p1 = t_lds[i1.x] * t_lds[i1.y];
                float p2 = t_lds[i2.x] * t_lds[i2.y];
                float p3 = t_lds[i3.x] * t_lds[i3.y];
                float p4 = t_lds[i4.x] * t_lds[i4.y];
                float p = ((p0 * p1) * (p2 * p3)) * p4;
                p = fminf(fmaxf(p, -0.999999f), 0.999999f);
                // check = 2*atanh(p) = ln((1+p)/(1-p))
                float check = __logf(__fdividef(1.0f + p, 1.0f - p));
                float wl  = in_row[n] * w_ch[n];   // L2 hit
                float wr0 = w_res[n];              // L2 hit
                float wr1 = w_res[NN + n];         // L2 hit
                float nv = wl + check + wr0 * vm[k] + wr1 * vmp[k];
                vmp[k] = vm[k];
                vm[k]  = nv;
            }
        }
        __syncthreads();
    }

    // epilogue: sigmoid(vm + input)
    #pragma unroll
    for (int k = 0; k < MAXK; ++k) {
        int n = tid + k * TPB;
        if (k < MAXK - 1 || n < NN) {
            float x = vm[k] + in_row[n];
            out[(size_t)row * NN + n] = __fdividef(1.0f, 1.0f + __expf(-x));
        }
    }
}

extern "C" void kernel_launch(void* const* d_in, const int* in_sizes, int n_in,
                              void* d_out, int out_size, void* d_ws, size_t ws_size,
                              hipStream_t stream) {
    const float* input_llr = (const float*)d_in[0];
    const float* w_ch      = (const float*)d_in[1];
    const float* w_res     = (const float*)d_in[2];
    const int*   cidx      = (const int*)d_in[3];
    // d_in[4] (var_index_tensor) is unused by the reference
    float* out = (float*)d_out;
    int batch = in_sizes[0] / NN;
    hipLaunchKernelGGL(ldpc_decode_kernel, dim3(batch), dim3(TPB), 0, stream,
                       input_llr, w_ch, w_res, cidx, out);
}

// Round 6
// 245.435 us; speedup vs baseline: 1.2769x; 1.2769x over previous
//
#include <hip/hip_runtime.h>

// LDPC neural BP decoder, MI355X. Round 6.
// Cross-round spill arithmetic: excess WRITE tracked the UNROLL FACTOR
// (R1 MAXK=17 -> ~2x17 f32/thr/iter spilled; R2/R5 MAXK=9 -> ~9-10 f32),
// not persistent state. The fully-unrolled phase-2 loop batches 9 k-steps'
// global loads (~126 VGPRs in flight) under a 64-reg budget -> whole state
// arrays spill. Fix: #pragma unroll 1 on phase 2; latency hidden by TLP
// (32 waves/CU), not ILP. vm/vmp (18 regs) persistent; wl/wr0/wr1 reloaded
// per iteration from L2-resident globals. One block per batch row; t-row in
// LDS; t computed per node per iteration (10x fewer tanh than per-edge).

#define NN    8448
#define MAXNB 10
#define TPB   1024
#define MAXK  9       // ceil(8448/1024); k=8 active only for tid<256
#define ITERS 5

__global__ __launch_bounds__(TPB)
void ldpc_decode_kernel(const float* __restrict__ input_llr,
                        const float* __restrict__ w_ch,
                        const float* __restrict__ w_res,   // [2][NN]
                        const int*   __restrict__ cidx,    // [NN][10]
                        float* __restrict__ out)
{
    __shared__ float t_lds[NN];
    const int row = blockIdx.x;
    const int tid = threadIdx.x;
    const float* __restrict__ in_row = input_llr + (size_t)row * NN;

    // persistent state: ONLY vm and vmp (18 VGPRs)
    float vm[MAXK], vmp[MAXK];

    // prologue: vm0 = weighted_llr = input * w_ch; prev = 0
    #pragma unroll
    for (int k = 0; k < MAXK; ++k) {
        int n = tid + k * TPB;
        vmp[k] = 0.0f;
        vm[k]  = 0.0f;
        if (k < MAXK - 1 || n < NN) {
            vm[k] = in_row[n] * w_ch[n];      // coalesced
        }
    }

    for (int it = 0; it < ITERS; ++it) {
        // phase 1: t[n] = tanh(clip(0.5*vm, +-9.9)) = 1 - 2/(exp(clip(vm,+-19.8))+1)
        #pragma unroll
        for (int k = 0; k < MAXK; ++k) {
            int n = tid + k * TPB;
            if (k < MAXK - 1 || n < NN) {
                float y = fminf(fmaxf(vm[k], -19.8f), 19.8f);
                float e = __expf(y);
                t_lds[n] = 1.0f - __fdividef(2.0f, e + 1.0f);
            }
        }
        __syncthreads();

        // phase 2: gather 10 t's, product, 2*atanh, residual update.
        // unroll 1: keeps in-flight load results bounded so the 64-VGPR
        // budget holds without spilling state arrays.
        #pragma unroll 1
        for (int k = 0; k < MAXK; ++k) {
            int n = tid + k * TPB;
            if (n < NN) {
                // 40*n is 8B-aligned -> five int2 loads (L2-resident, 338 KB table)
                const int2* ip = (const int2*)(cidx + n * MAXNB);
                int2 i0 = ip[0], i1 = ip[1], i2 = ip[2], i3 = ip[3], i4 = ip[4];
                float p0 = t_lds[i0.x] * t_lds[i0.y];
                float p1 = t_lds[i1.x] * t_lds[i1.y];
                float p2 = t_lds[i2.x] * t_lds[i2.y];
                float p3 = t_lds[i3.x] * t_lds[i3.y];
                float p4 = t_lds[i4.x] * t_lds[i4.y];
                float p = ((p0 * p1) * (p2 * p3)) * p4;
                p = fminf(fmaxf(p, -0.999999f), 0.999999f);
                // check = 2*atanh(p) = ln((1+p)/(1-p))
                float check = __logf(__fdividef(1.0f + p, 1.0f - p));
                float wl  = in_row[n] * w_ch[n];   // L2 hit
                float wr0 = w_res[n];              // L2 hit
                float wr1 = w_res[NN + n];         // L2 hit
                float nv = wl + check + wr0 * vm[k] + wr1 * vmp[k];
                vmp[k] = vm[k];
                vm[k]  = nv;
            }
        }
        __syncthreads();
    }

    // epilogue: sigmoid(vm + input)
    #pragma unroll
    for (int k = 0; k < MAXK; ++k) {
        int n = tid + k * TPB;
        if (k < MAXK - 1 || n < NN) {
            float x = vm[k] + in_row[n];
            out[(size_t)row * NN + n] = __fdividef(1.0f, 1.0f + __expf(-x));
        }
    }
}

extern "C" void kernel_launch(void* const* d_in, const int* in_sizes, int n_in,
                              void* d_out, int out_size, void* d_ws, size_t ws_size,
                              hipStream_t stream) {
    const float* input_llr = (const float*)d_in[0];
    const float* w_ch      = (const float*)d_in[1];
    const float* w_res     = (const float*)d_in[2];
    const int*   cidx      = (const int*)d_in[3];
    // d_in[4] (var_index_tensor) is unused by the reference
    float* out = (float*)d_out;
    int batch = in_sizes[0] / NN;
    hipLaunchKernelGGL(ldpc_decode_kernel, dim3(batch), dim3(TPB), 0, stream,
                       input_llr, w_ch, w_res, cidx, out);
}

// Round 7
// 194.015 us; speedup vs baseline: 1.6153x; 1.2650x over previous
//
#include <hip/hip_runtime.h>

// LDPC neural BP decoder, MI355X. Round 7.
// R6 landed (191 us, no spill, VGPR=36): LDS gather pipe is now the binding
// resource (62%), VALU 54% is half per-node overhead. Gather indices are
// row-independent -> process 2 batch rows per block with t interleaved
// (t2[n] = {t_r0, t_r1}): each random gather is one ds_read_b64 serving both
// rows (wave gather instrs halve), index loads/addressing paid once per pair.
// Dynamic LDS 67.6 KB (<=80 KB keeps 2 blocks/CU = 32 waves). State = four
// 9-arrays (constant row idx, dynamic k -- R6-proven in-reg pattern).
// Phase 2 stays #pragma unroll 1 (R6: unrolling it is what caused spill).

#define NN    8448
#define MAXNB 10
#define TPB   1024
#define MAXK  9       // ceil(8448/1024); k=8 active only for tid<256
#define ITERS 5
#define LDS_BYTES (NN * 2 * (int)sizeof(float))   // 67584

__global__ __launch_bounds__(TPB)
void ldpc_decode_kernel(const float* __restrict__ input_llr,
                        const float* __restrict__ w_ch,
                        const float* __restrict__ w_res,   // [2][NN]
                        const int*   __restrict__ cidx,    // [NN][10]
                        float* __restrict__ out)
{
    extern __shared__ float2 t2[];       // [NN], interleaved rows {r0, r1}
    const int tid  = threadIdx.x;
    const int row0 = blockIdx.x * 2;
    const float* __restrict__ in0 = input_llr + (size_t)row0 * NN;
    const float* __restrict__ in1 = in0 + NN;
    float* __restrict__ out0 = out + (size_t)row0 * NN;
    float* __restrict__ out1 = out0 + NN;

    // persistent state: vm/vmp for both rows (36 VGPRs)
    float vm0[MAXK], vm1[MAXK], vmp0[MAXK], vmp1[MAXK];

    // prologue: vm = input * w_ch; prev = 0
    #pragma unroll
    for (int k = 0; k < MAXK; ++k) {
        int n = tid + k * TPB;
        vmp0[k] = 0.0f; vmp1[k] = 0.0f;
        vm0[k] = 0.0f;  vm1[k] = 0.0f;
        if (k < MAXK - 1 || n < NN) {
            float wc = w_ch[n];
            vm0[k] = in0[n] * wc;
            vm1[k] = in1[n] * wc;
        }
    }

    for (int it = 0; it < ITERS; ++it) {
        // phase 1: t = tanh(clip(0.5*vm, +-9.9)) = 1 - 2/(exp(clip(vm,+-19.8))+1)
        #pragma unroll
        for (int k = 0; k < MAXK; ++k) {
            int n = tid + k * TPB;
            if (k < MAXK - 1 || n < NN) {
                float y0 = fminf(fmaxf(vm0[k], -19.8f), 19.8f);
                float y1 = fminf(fmaxf(vm1[k], -19.8f), 19.8f);
                float t0 = 1.0f - __fdividef(2.0f, __expf(y0) + 1.0f);
                float t1 = 1.0f - __fdividef(2.0f, __expf(y1) + 1.0f);
                t2[n] = make_float2(t0, t1);   // ds_write_b64, stride-1
            }
        }
        __syncthreads();

        // phase 2: 10 b64 gathers serve both rows; indices/addressing paid once
        #pragma unroll 1
        for (int k = 0; k < MAXK; ++k) {
            int n = tid + k * TPB;
            if (n < NN) {
                const int2* ip = (const int2*)(cidx + n * MAXNB);
                int2 i0 = ip[0], i1 = ip[1], i2 = ip[2], i3 = ip[3], i4 = ip[4];
                float2 a0 = t2[i0.x], b0 = t2[i0.y];
                float2 a1 = t2[i1.x], b1 = t2[i1.y];
                float2 a2 = t2[i2.x], b2 = t2[i2.y];
                float2 a3 = t2[i3.x], b3 = t2[i3.y];
                float2 a4 = t2[i4.x], b4 = t2[i4.y];
                float p0 = (a0.x * b0.x) * (a1.x * b1.x);
                float q0 = (a2.x * b2.x) * (a3.x * b3.x);
                float p1 = (a0.y * b0.y) * (a1.y * b1.y);
                float q1 = (a2.y * b2.y) * (a3.y * b3.y);
                float pr0 = (p0 * q0) * (a4.x * b4.x);
                float pr1 = (p1 * q1) * (a4.y * b4.y);
                pr0 = fminf(fmaxf(pr0, -0.999999f), 0.999999f);
                pr1 = fminf(fmaxf(pr1, -0.999999f), 0.999999f);
                float check0 = __logf(__fdividef(1.0f + pr0, 1.0f - pr0));
                float check1 = __logf(__fdividef(1.0f + pr1, 1.0f - pr1));
                float wc  = w_ch[n];               // L2 hit
                float wr0 = w_res[n];              // L2 hit
                float wr1 = w_res[NN + n];         // L2 hit
                float nv0 = in0[n] * wc + check0 + wr0 * vm0[k] + wr1 * vmp0[k];
                float nv1 = in1[n] * wc + check1 + wr0 * vm1[k] + wr1 * vmp1[k];
                vmp0[k] = vm0[k];  vm0[k] = nv0;
                vmp1[k] = vm1[k];  vm1[k] = nv1;
            }
        }
        __syncthreads();
    }

    // epilogue: sigmoid(vm + input)
    #pragma unroll
    for (int k = 0; k < MAXK; ++k) {
        int n = tid + k * TPB;
        if (k < MAXK - 1 || n < NN) {
            float x0 = vm0[k] + in0[n];
            float x1 = vm1[k] + in1[n];
            out0[n] = __fdividef(1.0f, 1.0f + __expf(-x0));
            out1[n] = __fdividef(1.0f, 1.0f + __expf(-x1));
        }
    }
}

extern "C" void kernel_launch(void* const* d_in, const int* in_sizes, int n_in,
                              void* d_out, int out_size, void* d_ws, size_t ws_size,
                              hipStream_t stream) {
    const float* input_llr = (const float*)d_in[0];
    const float* w_ch      = (const float*)d_in[1];
    const float* w_res     = (const float*)d_in[2];
    const int*   cidx      = (const int*)d_in[3];
    // d_in[4] (var_index_tensor) is unused by the reference
    float* out = (float*)d_out;
    int batch = in_sizes[0] / NN;

    // allow >64 KB dynamic LDS (67.6 KB); host-side, idempotent, capture-safe
    hipFuncSetAttribute((const void*)ldpc_decode_kernel,
                        hipFuncAttributeMaxDynamicSharedMemorySize, LDS_BYTES);

    hipLaunchKernelGGL(ldpc_decode_kernel, dim3(batch / 2), dim3(TPB),
                       LDS_BYTES, stream, input_llr, w_ch, w_res, cidx, out);
}